// Round 9
// baseline (1755.281 us; speedup 1.0000x reference)
//
#include <hip/hip_runtime.h>
#include <hip/hip_bf16.h>
#include <cstdint>
#include <cstddef>

#define Bsz  256
#define Tn   4096
#define In   8
#define Hn   32
#define TGTn 8

typedef float v2f __attribute__((ext_vector_type(2)));

__device__ __forceinline__ v2f pk_fma(v2f a, v2f b, v2f c) {
    return __builtin_elementwise_fma(a, b, c);
}
__device__ __forceinline__ v2f pk_mul(v2f a, v2f b) { return a * b; }

// DPP rotate within 16-lane rows; direction convention handled by probing.
template<int N>
__device__ __forceinline__ float dpp_ror(float x) {
    int xi = __float_as_int(x);
    int r = __builtin_amdgcn_update_dpp(xi, xi, 0x120 + N, 0xF, 0xF, false);
    return __int_as_float(r);
}

// x_l + x_{l^32} in every lane (hazards managed by compiler — builtin, not asm).
__device__ __forceinline__ float half_sum(float x) {
    auto r = __builtin_amdgcn_permlane32_swap(__float_as_int(x), __float_as_int(x),
                                              false, false);
    return __int_as_float((int)r[0]) + __int_as_float((int)r[1]);
}

// Unordered pair {f(lane&15), f(16+(lane&15))}; caller probes slot order.
__device__ __forceinline__ void row16_pair(float x, float& a_out, float& b_out) {
    auto r = __builtin_amdgcn_permlane16_swap(__float_as_int(x), __float_as_int(x),
                                              false, false);
    a_out = __int_as_float((int)r[0]);
    b_out = __int_as_float((int)r[1]);
}

// Array-based butterfly — used ONLY for the init-time probe (cold code).
// Must match the macro's H0..H7 assignments exactly.
__device__ __forceinline__ void gather16_probe(float v, v2f H[8]) {
    v2f G0; G0.x = v;                G0.y = dpp_ror<1>(v);
    v2f G1; G1.x = dpp_ror<2>(G0.x); G1.y = dpp_ror<2>(G0.y);
    v2f G2; G2.x = dpp_ror<4>(G0.x); G2.y = dpp_ror<4>(G0.y);
    v2f G3; G3.x = dpp_ror<4>(G1.x); G3.y = dpp_ror<4>(G1.y);
    v2f G4; G4.x = dpp_ror<8>(G0.x); G4.y = dpp_ror<8>(G0.y);
    v2f G5; G5.x = dpp_ror<8>(G1.x); G5.y = dpp_ror<8>(G1.y);
    v2f G6; G6.x = dpp_ror<8>(G2.x); G6.y = dpp_ror<8>(G2.y);
    v2f G7; G7.x = dpp_ror<8>(G3.x); G7.y = dpp_ror<8>(G3.y);
    H[0]=G0; H[1]=G1; H[2]=G2; H[3]=G3; H[4]=G4; H[5]=G5; H[6]=G6; H[7]=G7;
}

__device__ __forceinline__ float rcpf(float x) { return __builtin_amdgcn_rcpf(x); }
__device__ __forceinline__ float sigm(float x) { return rcpf(1.f + __expf(-x)); }
__device__ __forceinline__ float tanhfast(float x) {
    float e = __expf(2.f * x);
    return 1.f - 2.f * rcpf(e + 1.f);
}

// W = w_ih @ E : [96,8]
__global__ void fuse_wih_kernel(const float* __restrict__ w_ih,
                                const float* __restrict__ E,
                                float* __restrict__ Wf) {
    int tid = threadIdx.x;                // 768 threads
    int g = tid >> 3, i = tid & 7;
    float acc = 0.f;
#pragma unroll
    for (int k = 0; k < Hn; ++k)
        acc = fmaf(w_ih[g * Hn + k], E[k * In + i], acc);
    Wf[g * In + i] = acc;
}

// One step of the GRU. All operands are NAMED registers. XNEXT = ring slot
// holding x[s+1]; XREFILL = slot freed this step (gets x[s+8]).
#define GRU_STEP(XNEXT, XREFILL, DO_REFILL)                                          \
  {                                                                                  \
    v2f ar0 = pk_fma(H0, whr0, pk_fma(H2, whr2, pk_fma(H4, whr4, pk_mul(H6, whr6))));\
    v2f ar1 = pk_fma(H1, whr1, pk_fma(H3, whr3, pk_fma(H5, whr5, pk_mul(H7, whr7))));\
    v2f az0 = pk_fma(H0, whz0, pk_fma(H2, whz2, pk_fma(H4, whz4, pk_mul(H6, whz6))));\
    v2f az1 = pk_fma(H1, whz1, pk_fma(H3, whz3, pk_fma(H5, whz5, pk_mul(H7, whz7))));\
    v2f an0 = pk_fma(H0, whn0, pk_fma(H2, whn2, pk_fma(H4, whn4, pk_mul(H6, whn6))));\
    v2f an1 = pk_fma(H1, whn1, pk_fma(H3, whn3, pk_fma(H5, whn5, pk_mul(H7, whn7))));\
    v2f art = ar0 + ar1;                                                             \
    v2f azt = az0 + az1;                                                             \
    v2f ant = an0 + an1;                                                             \
    float pr  = art.x + art.y + axr;                                                 \
    float pz  = azt.x + azt.y + axz;                                                 \
    float phn = ant.x + ant.y + bhnh;                                                \
    float cr  = half_sum(pr);                                                        \
    float cz  = half_sum(pz);                                                        \
    float chn = half_sum(phn);                                                       \
    float r = sigm(cr);                                                              \
    float z = sigm(cz);                                                              \
    float n = tanhfast(cxn + r * chn);                                               \
    hj = __builtin_fmaf(z, hj - n, n);                                               \
    float va, vb;                                                                    \
    row16_pair(hj, va, vb);                                                          \
    float gv = pick_a ? va : vb;          /* = h[grp*16 + (lane&15)] */              \
    H0 = v2f{gv, dpp_ror<1>(gv)};                                                    \
    H1 = v2f{dpp_ror<2>(H0.x), dpp_ror<2>(H0.y)};                                    \
    H2 = v2f{dpp_ror<4>(H0.x), dpp_ror<4>(H0.y)};                                    \
    H3 = v2f{dpp_ror<4>(H1.x), dpp_ror<4>(H1.y)};                                    \
    H4 = v2f{dpp_ror<8>(H0.x), dpp_ror<8>(H0.y)};                                    \
    H5 = v2f{dpp_ror<8>(H1.x), dpp_ror<8>(H1.y)};                                    \
    H6 = v2f{dpp_ror<8>(H2.x), dpp_ror<8>(H2.y)};                                    \
    H7 = v2f{dpp_ror<8>(H3.x), dpp_ror<8>(H3.y)};                                    \
    *latp = hj;                                                                      \
    latp += Hn;                                                                      \
    {                                                                                \
      v2f nx0 = v2f{XNEXT.x, XNEXT.y}, nx1 = v2f{XNEXT.z, XNEXT.w};                  \
      v2f ta = pk_fma(nx0, wxr0, pk_mul(nx1, wxr1));                                 \
      axr = ta.x + ta.y + brh;                                                       \
      v2f tb = pk_fma(nx0, wxz0, pk_mul(nx1, wxz1));                                 \
      axz = tb.x + tb.y + bzh;                                                       \
      v2f tc = pk_fma(nx0, wxn0, pk_mul(nx1, wxn1));                                 \
      cxn = half_sum(tc.x + tc.y + bxnh);                                            \
    }                                                                                \
    if (DO_REFILL) { XREFILL = *(const float4*)refp; refp += In; }                   \
  }

// 8 waves per block (512 threads) = 2 waves per SIMD: two independent
// recurrence chains interleave issue on each SIMD, hiding each other's
// dependency stalls (the measured profile: ~120 cyc issue + ~450 cyc stall
// per step at 1 wave/SIMD). Each wave owns one batch element; waves never
// communicate (no LDS, no barriers).
#define KEEP(v) asm volatile("" : "+v"(v))
__attribute__((amdgpu_flat_work_group_size(512, 512)))
__global__ void gru_kernel(const float* __restrict__ x,     // [B,T,8]
                           const float* __restrict__ Wf,    // [96,8] fused w_ih@E
                           const float* __restrict__ w_hh,  // [96,32]
                           const float* __restrict__ b_ih,  // [96]
                           const float* __restrict__ b_hh,  // [96]
                           float* __restrict__ latents) {   // [B,T,32]
    const int lane = threadIdx.x & 63;
    const int grp  = lane >> 5;     // K/I half this lane accumulates
    const int j    = lane & 31;     // hidden row this lane produces
    const int r16  = lane & 15;
    const int b    = blockIdx.x * 8 + (threadIdx.x >> 6);   // wave -> batch

    // ---- self-calibration: probe the hardware's permutation conventions ----
    int sidx[16];
    {
        v2f P[8];
        gather16_probe((float)r16, P);
#pragma unroll
        for (int q = 0; q < 8; ++q) {
            sidx[2*q]   = (int)P[q].x;
            sidx[2*q+1] = (int)P[q].y;
        }
    }
    bool pick_a;
    {
        float va, vb;
        row16_pair((float)j, va, vb);
        pick_a = ((int)va == grp * 16 + r16);
    }

    // ---- weights into NAMED registers, permuted to the probed lane order ----
    v2f whr0, whr1, whr2, whr3, whr4, whr5, whr6, whr7;
    v2f whz0, whz1, whz2, whz3, whz4, whz5, whz6, whz7;
    v2f whn0, whn1, whn2, whn3, whn4, whn5, whn6, whn7;
#define LOADW(Q)                                                                  \
    {                                                                             \
        const int c0 = grp * 16 + sidx[2*Q], c1 = grp * 16 + sidx[2*Q+1];         \
        whr##Q = v2f{w_hh[(0*Hn + j)*Hn + c0], w_hh[(0*Hn + j)*Hn + c1]};         \
        whz##Q = v2f{w_hh[(1*Hn + j)*Hn + c0], w_hh[(1*Hn + j)*Hn + c1]};         \
        whn##Q = v2f{w_hh[(2*Hn + j)*Hn + c0], w_hh[(2*Hn + j)*Hn + c1]};         \
        KEEP(whr##Q); KEEP(whz##Q); KEEP(whn##Q);                                 \
    }
    LOADW(0) LOADW(1) LOADW(2) LOADW(3) LOADW(4) LOADW(5) LOADW(6) LOADW(7)
#undef LOADW

    v2f wxr0 = v2f{Wf[(0*Hn+j)*In + grp*4 + 0], Wf[(0*Hn+j)*In + grp*4 + 1]};
    v2f wxr1 = v2f{Wf[(0*Hn+j)*In + grp*4 + 2], Wf[(0*Hn+j)*In + grp*4 + 3]};
    v2f wxz0 = v2f{Wf[(1*Hn+j)*In + grp*4 + 0], Wf[(1*Hn+j)*In + grp*4 + 1]};
    v2f wxz1 = v2f{Wf[(1*Hn+j)*In + grp*4 + 2], Wf[(1*Hn+j)*In + grp*4 + 3]};
    v2f wxn0 = v2f{Wf[(2*Hn+j)*In + grp*4 + 0], Wf[(2*Hn+j)*In + grp*4 + 1]};
    v2f wxn1 = v2f{Wf[(2*Hn+j)*In + grp*4 + 2], Wf[(2*Hn+j)*In + grp*4 + 3]};
    KEEP(wxr0); KEEP(wxr1); KEEP(wxz0); KEEP(wxz1); KEEP(wxn0); KEEP(wxn1);

    // half-biases: each K-half carries 0.5*b; the permlane half-sum restores b
    float brh  = 0.5f * (b_ih[j]        + b_hh[j]);
    float bzh  = 0.5f * (b_ih[Hn + j]   + b_hh[Hn + j]);
    float bxnh = 0.5f * b_ih[2*Hn + j];
    float bhnh = 0.5f * b_hh[2*Hn + j];
    KEEP(brh); KEEP(bzh); KEEP(bxnh); KEEP(bhnh);

    const float* xb = x + (size_t)b * Tn * In;
    float* latp     = latents + (size_t)b * Tn * Hn + j;   // advances Hn/step
    const float* refp = xb + (size_t)8 * In + grp * 4;     // next refill = x[8]

    float hj = 0.f;
    v2f H0{0.f,0.f}, H1{0.f,0.f}, H2{0.f,0.f}, H3{0.f,0.f},
        H4{0.f,0.f}, H5{0.f,0.f}, H6{0.f,0.f}, H7{0.f,0.f};

    // ---- 8-deep x ring in NAMED float4 slots ----
    float4 x0 = *(const float4*)&xb[0*In + grp*4];
    float4 x1 = *(const float4*)&xb[1*In + grp*4];
    float4 x2 = *(const float4*)&xb[2*In + grp*4];
    float4 x3 = *(const float4*)&xb[3*In + grp*4];
    float4 x4 = *(const float4*)&xb[4*In + grp*4];
    float4 x5 = *(const float4*)&xb[5*In + grp*4];
    float4 x6 = *(const float4*)&xb[6*In + grp*4];
    float4 x7 = *(const float4*)&xb[7*In + grp*4];

    float axr, axz, cxn;
    {   // pre-activations for step 0 (from slot x0)
        v2f nx0 = v2f{x0.x, x0.y}, nx1 = v2f{x0.z, x0.w};
        v2f ta = pk_fma(nx0, wxr0, pk_mul(nx1, wxr1));
        axr = ta.x + ta.y + brh;
        v2f tb = pk_fma(nx0, wxz0, pk_mul(nx1, wxz1));
        axz = tb.x + tb.y + bzh;
        v2f tc = pk_fma(nx0, wxn0, pk_mul(nx1, wxn1));
        cxn = half_sum(tc.x + tc.y + bxnh);
    }

    // main loop: steps 0..4087 (511 groups of 8), refilling x[s+8] each step
#pragma unroll 1
    for (int s0 = 0; s0 < Tn - 8; s0 += 8) {
        GRU_STEP(x1, x0, true)
        GRU_STEP(x2, x1, true)
        GRU_STEP(x3, x2, true)
        GRU_STEP(x4, x3, true)
        GRU_STEP(x5, x4, true)
        GRU_STEP(x6, x5, true)
        GRU_STEP(x7, x6, true)
        GRU_STEP(x0, x7, true)
    }
    // epilogue: steps 4088..4095, no refills (slots hold x[4088..4095])
    GRU_STEP(x1, x0, false)
    GRU_STEP(x2, x1, false)
    GRU_STEP(x3, x2, false)
    GRU_STEP(x4, x3, false)
    GRU_STEP(x5, x4, false)
    GRU_STEP(x6, x5, false)
    GRU_STEP(x7, x6, false)
    GRU_STEP(x0, x7, false)
}
#undef KEEP

// outputs[b,t,o] = sum_h latents[b,t,h] * E[h,o]
__global__ void decode_kernel(const float* __restrict__ lat,
                              const float* __restrict__ E,
                              float* __restrict__ out) {
    __shared__ float ldsE[Hn * TGTn];
    int tid = threadIdx.x;
    if (tid < Hn * TGTn) ldsE[tid] = E[tid];
    __syncthreads();
    size_t idx = (size_t)blockIdx.x * 256 + tid;   // over B*T*8
    int o      = (int)(idx & (TGTn - 1));
    size_t row = idx >> 3;
    const float* lrow = lat + row * Hn;
    float acc = 0.f;
#pragma unroll
    for (int h = 0; h < Hn; ++h)
        acc = fmaf(lrow[h], ldsE[h * TGTn + o], acc);
    out[idx] = acc;
}

extern "C" void kernel_launch(void* const* d_in, const int* in_sizes, int n_in,
                              void* d_out, int out_size, void* d_ws, size_t ws_size,
                              hipStream_t stream) {
    const float* x    = (const float*)d_in[0];
    const float* E    = (const float*)d_in[1];
    const float* w_ih = (const float*)d_in[2];
    const float* w_hh = (const float*)d_in[3];
    const float* b_ih = (const float*)d_in[4];
    const float* b_hh = (const float*)d_in[5];

    float* out = (float*)d_out;                          // [B,T,8]
    float* lat = out + (size_t)Bsz * Tn * TGTn;          // [B,T,32]
    float* Wf  = (float*)d_ws;                           // [96,8]

    fuse_wih_kernel<<<1, 768, 0, stream>>>(w_ih, E, Wf);
    gru_kernel<<<Bsz / 8, 512, 0, stream>>>(x, Wf, w_hh, b_ih, b_hh, lat);
    decode_kernel<<<(Bsz * Tn * TGTn) / 256, 256, 0, stream>>>(lat, E, out);
}

// Round 10
// 1098.832 us; speedup vs baseline: 1.5974x; 1.5974x over previous
//
#include <hip/hip_runtime.h>
#include <hip/hip_bf16.h>
#include <cstdint>
#include <cstddef>

#define Bsz  256
#define Tn   4096
#define In   8
#define Hn   32
#define TGTn 8

typedef float v2f __attribute__((ext_vector_type(2)));

__device__ __forceinline__ v2f pk_fma(v2f a, v2f b, v2f c) {
    return __builtin_elementwise_fma(a, b, c);
}
__device__ __forceinline__ v2f pk_mul(v2f a, v2f b) { return a * b; }

// DPP rotate within 16-lane rows; direction convention handled by probing.
template<int N>
__device__ __forceinline__ float dpp_ror(float x) {
    int xi = __float_as_int(x);
    int r = __builtin_amdgcn_update_dpp(xi, xi, 0x120 + N, 0xF, 0xF, false);
    return __int_as_float(r);
}

// x_l + x_{l^32} in every lane (hazard handling by compiler builtin).
__device__ __forceinline__ float half_sum(float x) {
    auto r = __builtin_amdgcn_permlane32_swap(__float_as_int(x), __float_as_int(x),
                                              false, false);
    return __int_as_float((int)r[0]) + __int_as_float((int)r[1]);
}

// Unordered pair {f(lane&15), f(16+(lane&15))}; caller probes slot order.
__device__ __forceinline__ void row16_pair(float x, float& a_out, float& b_out) {
    auto r = __builtin_amdgcn_permlane16_swap(__float_as_int(x), __float_as_int(x),
                                              false, false);
    a_out = __int_as_float((int)r[0]);
    b_out = __int_as_float((int)r[1]);
}

// Array-based butterfly — init-time probe only; must match BCAST's H-builds.
__device__ __forceinline__ void gather16_probe(float v, v2f H[8]) {
    v2f G0; G0.x = v;                G0.y = dpp_ror<1>(v);
    v2f G1; G1.x = dpp_ror<2>(G0.x); G1.y = dpp_ror<2>(G0.y);
    v2f G2; G2.x = dpp_ror<4>(G0.x); G2.y = dpp_ror<4>(G0.y);
    v2f G3; G3.x = dpp_ror<4>(G1.x); G3.y = dpp_ror<4>(G1.y);
    v2f G4; G4.x = dpp_ror<8>(G0.x); G4.y = dpp_ror<8>(G0.y);
    v2f G5; G5.x = dpp_ror<8>(G1.x); G5.y = dpp_ror<8>(G1.y);
    v2f G6; G6.x = dpp_ror<8>(G2.x); G6.y = dpp_ror<8>(G2.y);
    v2f G7; G7.x = dpp_ror<8>(G3.x); G7.y = dpp_ror<8>(G3.y);
    H[0]=G0; H[1]=G1; H[2]=G2; H[3]=G3; H[4]=G4; H[5]=G5; H[6]=G6; H[7]=G7;
}

__device__ __forceinline__ float rcpf(float x) { return __builtin_amdgcn_rcpf(x); }
__device__ __forceinline__ float sigm(float x) { return rcpf(1.f + __expf(-x)); }
__device__ __forceinline__ float tanhfast(float x) {
    float e = __expf(2.f * x);
    return 1.f - 2.f * rcpf(e + 1.f);
}

// W = w_ih @ E : [96,8]
__global__ void fuse_wih_kernel(const float* __restrict__ w_ih,
                                const float* __restrict__ E,
                                float* __restrict__ Wf) {
    int tid = threadIdx.x;                // 768 threads
    int g = tid >> 3, i = tid & 7;
    float acc = 0.f;
#pragma unroll
    for (int k = 0; k < Hn; ++k)
        acc = fmaf(w_ih[g * Hn + k], E[k * In + i], acc);
    Wf[g * In + i] = acc;
}

// gx[b, trel, j, {r,z,n}] = Wf_row . x[b, t0+trel] + bias  (time-parallel,
// memory-bound; removes the whole x-path from the recurrent wave).
__global__ void gx_kernel(const float* __restrict__ x,
                          const float* __restrict__ Wf,
                          const float* __restrict__ b_ih,
                          const float* __restrict__ b_hh,
                          float* __restrict__ gx,
                          int t0, int Tc) {
    int local = blockIdx.x * 256 + threadIdx.x;   // over Tc*32
    int b     = blockIdx.y;
    int j     = local & 31;
    int trel  = local >> 5;
    const float* xr = x + ((size_t)b * Tn + t0 + trel) * In;
    float x0 = xr[0], x1 = xr[1], x2 = xr[2], x3 = xr[3],
          x4 = xr[4], x5 = xr[5], x6 = xr[6], x7 = xr[7];
    const float* wr = &Wf[(0 * Hn + j) * In];
    const float* wz = &Wf[(1 * Hn + j) * In];
    const float* wn = &Wf[(2 * Hn + j) * In];
    float ar = b_ih[j] + b_hh[j];
    float az = b_ih[Hn + j] + b_hh[Hn + j];
    float an = b_ih[2 * Hn + j];              // b_hh_n stays inside r*(...)
    ar = fmaf(wr[0],x0,ar); ar = fmaf(wr[1],x1,ar); ar = fmaf(wr[2],x2,ar); ar = fmaf(wr[3],x3,ar);
    ar = fmaf(wr[4],x4,ar); ar = fmaf(wr[5],x5,ar); ar = fmaf(wr[6],x6,ar); ar = fmaf(wr[7],x7,ar);
    az = fmaf(wz[0],x0,az); az = fmaf(wz[1],x1,az); az = fmaf(wz[2],x2,az); az = fmaf(wz[3],x3,az);
    az = fmaf(wz[4],x4,az); az = fmaf(wz[5],x5,az); az = fmaf(wz[6],x6,az); az = fmaf(wz[7],x7,az);
    an = fmaf(wn[0],x0,an); an = fmaf(wn[1],x1,an); an = fmaf(wn[2],x2,an); an = fmaf(wn[3],x3,an);
    an = fmaf(wn[4],x4,an); an = fmaf(wn[5],x5,an); an = fmaf(wn[6],x6,an); an = fmaf(wn[7],x7,an);
    float* o = gx + (((size_t)b * Tc + trel) * Hn + j) * 3;
    o[0] = ar; o[1] = az; o[2] = an;
}

// Rebuild H0..H7 (all 16 h values of this lane's K-half, probed order) from hj.
#define BCAST()                                                                      \
  {                                                                                  \
    float va, vb;                                                                    \
    row16_pair(hj, va, vb);                                                          \
    float gv = pick_a ? va : vb;          /* = h[grp*16 + (lane&15)] */              \
    H0 = v2f{gv, dpp_ror<1>(gv)};                                                    \
    H1 = v2f{dpp_ror<2>(H0.x), dpp_ror<2>(H0.y)};                                    \
    H2 = v2f{dpp_ror<4>(H0.x), dpp_ror<4>(H0.y)};                                    \
    H3 = v2f{dpp_ror<4>(H1.x), dpp_ror<4>(H1.y)};                                    \
    H4 = v2f{dpp_ror<8>(H0.x), dpp_ror<8>(H0.y)};                                    \
    H5 = v2f{dpp_ror<8>(H1.x), dpp_ror<8>(H1.y)};                                    \
    H6 = v2f{dpp_ror<8>(H2.x), dpp_ror<8>(H2.y)};                                    \
    H7 = v2f{dpp_ror<8>(H3.x), dpp_ror<8>(H3.y)};                                    \
  }

// One GRU step: consume gx slot (GA,GB,GC) for step s, then refill it with
// step s+4's values (4-deep prefetch; tail overruns land in the pad).
#define GRU_STEP(GA, GB, GC)                                                         \
  {                                                                                  \
    v2f ar = pk_fma(H0, whr0, pk_fma(H1, whr1, pk_fma(H2, whr2, pk_fma(H3, whr3,     \
             pk_fma(H4, whr4, pk_fma(H5, whr5, pk_fma(H6, whr6, pk_mul(H7, whr7)))))))); \
    v2f az = pk_fma(H0, whz0, pk_fma(H1, whz1, pk_fma(H2, whz2, pk_fma(H3, whz3,     \
             pk_fma(H4, whz4, pk_fma(H5, whz5, pk_fma(H6, whz6, pk_mul(H7, whz7)))))))); \
    v2f an = pk_fma(H0, whn0, pk_fma(H1, whn1, pk_fma(H2, whn2, pk_fma(H3, whn3,     \
             pk_fma(H4, whn4, pk_fma(H5, whn5, pk_fma(H6, whn6, pk_mul(H7, whn7)))))))); \
    float cr  = half_sum(ar.x + ar.y) + GA;                                          \
    float cz  = half_sum(az.x + az.y) + GB;                                          \
    float chn = half_sum(an.x + an.y) + bhn;                                         \
    float r = sigm(cr);                                                              \
    float z = sigm(cz);                                                              \
    float n = tanhfast(__builtin_fmaf(r, chn, GC));                                  \
    hj = __builtin_fmaf(z, hj - n, n);                                               \
    BCAST()                                                                          \
    *latp = hj;                                                                      \
    latp += Hn;                                                                      \
    GA = refp[0]; GB = refp[1]; GC = refp[2];                                        \
    refp += 3 * Hn;                                                                  \
  }

#define KEEP(v) asm volatile("" : "+v"(v))
__attribute__((amdgpu_flat_work_group_size(64, 64), amdgpu_waves_per_eu(1, 1)))
__global__ void gru_kernel(const float* __restrict__ gx,    // [B,Tc,32,3]
                           const float* __restrict__ w_hh,  // [96,32]
                           const float* __restrict__ b_hh,  // [96]
                           float* __restrict__ hbuf,        // [B,32] carry
                           float* __restrict__ latents,     // [B,T,32]
                           int t0, int Tc, int first) {
    const int lane = threadIdx.x & 63;
    const int grp  = lane >> 5;     // K-half this lane accumulates
    const int j    = lane & 31;     // hidden row this lane produces
    const int r16  = lane & 15;
    const int b    = blockIdx.x;

    // ---- probe hardware permutation conventions ----
    int sidx[16];
    {
        v2f P[8];
        gather16_probe((float)r16, P);
#pragma unroll
        for (int q = 0; q < 8; ++q) {
            sidx[2*q]   = (int)P[q].x;
            sidx[2*q+1] = (int)P[q].y;
        }
    }
    bool pick_a;
    {
        float va, vb;
        row16_pair((float)j, va, vb);
        pick_a = ((int)va == grp * 16 + r16);
    }

    // ---- recurrent weights into NAMED registers, probed order ----
    v2f whr0, whr1, whr2, whr3, whr4, whr5, whr6, whr7;
    v2f whz0, whz1, whz2, whz3, whz4, whz5, whz6, whz7;
    v2f whn0, whn1, whn2, whn3, whn4, whn5, whn6, whn7;
#define LOADW(Q)                                                                  \
    {                                                                             \
        const int c0 = grp * 16 + sidx[2*Q], c1 = grp * 16 + sidx[2*Q+1];         \
        whr##Q = v2f{w_hh[(0*Hn + j)*Hn + c0], w_hh[(0*Hn + j)*Hn + c1]};         \
        whz##Q = v2f{w_hh[(1*Hn + j)*Hn + c0], w_hh[(1*Hn + j)*Hn + c1]};         \
        whn##Q = v2f{w_hh[(2*Hn + j)*Hn + c0], w_hh[(2*Hn + j)*Hn + c1]};         \
        KEEP(whr##Q); KEEP(whz##Q); KEEP(whn##Q);                                 \
    }
    LOADW(0) LOADW(1) LOADW(2) LOADW(3) LOADW(4) LOADW(5) LOADW(6) LOADW(7)
#undef LOADW

    float bhn = b_hh[2 * Hn + j];
    KEEP(bhn);

    float* latp = latents + (size_t)b * Tn * Hn + (size_t)t0 * Hn + j;
    const float* refp = gx + ((size_t)b * Tc) * (3 * Hn) + j * 3;

    float hj = first ? 0.f : hbuf[b * Hn + j];
    v2f H0, H1, H2, H3, H4, H5, H6, H7;
    BCAST()

    // ---- 4-deep gx prefetch into named slots (steps 0..3) ----
    float g0a = refp[0], g0b = refp[1], g0c = refp[2]; refp += 3 * Hn;
    float g1a = refp[0], g1b = refp[1], g1c = refp[2]; refp += 3 * Hn;
    float g2a = refp[0], g2b = refp[1], g2c = refp[2]; refp += 3 * Hn;
    float g3a = refp[0], g3b = refp[1], g3c = refp[2]; refp += 3 * Hn;

#pragma unroll 1
    for (int it = 0; it < Tc / 8; ++it) {
        GRU_STEP(g0a, g0b, g0c)
        GRU_STEP(g1a, g1b, g1c)
        GRU_STEP(g2a, g2b, g2c)
        GRU_STEP(g3a, g3b, g3c)
        GRU_STEP(g0a, g0b, g0c)
        GRU_STEP(g1a, g1b, g1c)
        GRU_STEP(g2a, g2b, g2c)
        GRU_STEP(g3a, g3b, g3c)
    }

    if (grp == 0) hbuf[b * Hn + j] = hj;   // carry h to next chunk
}
#undef KEEP

// outputs[b,t,o] = sum_h latents[b,t,h] * E[h,o]
__global__ void decode_kernel(const float* __restrict__ lat,
                              const float* __restrict__ E,
                              float* __restrict__ out) {
    __shared__ float ldsE[Hn * TGTn];
    int tid = threadIdx.x;
    if (tid < Hn * TGTn) ldsE[tid] = E[tid];
    __syncthreads();
    size_t idx = (size_t)blockIdx.x * 256 + tid;   // over B*T*8
    int o      = (int)(idx & (TGTn - 1));
    size_t row = idx >> 3;
    const float* lrow = lat + row * Hn;
    float acc = 0.f;
#pragma unroll
    for (int h = 0; h < Hn; ++h)
        acc = fmaf(lrow[h], ldsE[h * TGTn + o], acc);
    out[idx] = acc;
}

extern "C" void kernel_launch(void* const* d_in, const int* in_sizes, int n_in,
                              void* d_out, int out_size, void* d_ws, size_t ws_size,
                              hipStream_t stream) {
    const float* x    = (const float*)d_in[0];
    const float* E    = (const float*)d_in[1];
    const float* w_ih = (const float*)d_in[2];
    const float* w_hh = (const float*)d_in[3];
    const float* b_ih = (const float*)d_in[4];
    const float* b_hh = (const float*)d_in[5];

    float* out  = (float*)d_out;                         // [B,T,8]
    float* lat  = out + (size_t)Bsz * Tn * TGTn;         // [B,T,32]
    float* Wf   = (float*)d_ws;                          // [96,8]
    float* hbuf = Wf + 1024;                             // [256,32]
    float* gx   = hbuf + Bsz * Hn;                       // chunk buffer

    // largest T-chunk whose gx buffer (+4-step pad) fits the workspace;
    // prefer <=1024 so each ~100MB chunk stays L3-resident.
    size_t avail = (ws_size / 4 > (size_t)(1024 + Bsz * Hn))
                 ? ws_size / 4 - (1024 + Bsz * Hn) : 0;
    int Tc = 1024;
    while (Tc > 8 && (size_t)Bsz * Tc * 3 * Hn + 4 * 3 * Hn > avail) Tc >>= 1;

    fuse_wih_kernel<<<1, 768, 0, stream>>>(w_ih, E, Wf);
    for (int t0 = 0; t0 < Tn; t0 += Tc) {
        gx_kernel<<<dim3(Tc * Hn / 256, Bsz), 256, 0, stream>>>(
            x, Wf, b_ih, b_hh, gx, t0, Tc);
        gru_kernel<<<Bsz, 64, 0, stream>>>(
            gx, w_hh, b_hh, hbuf, lat, t0, Tc, t0 == 0 ? 1 : 0);
    }
    decode_kernel<<<(Bsz * Tn * TGTn) / 256, 256, 0, stream>>>(lat, E, out);
}